// Round 8
// baseline (511.434 us; speedup 1.0000x reference)
//
#include <hip/hip_runtime.h>
#include <hip/hip_bf16.h>
#include <math.h>

#define B_   16
#define S_   4096
#define D_   768
#define H_   384
#define NTOK (B_ * S_)
#define KTOP 40
#define NCAND 128          // filter keeps top-128 per batch; true top-40 margin ~100x
#define NTILES 24          // 384/16 n-tiles
#define KCH    24          // 768/32 k-chunks

typedef __attribute__((ext_vector_type(8))) short bf16x8;
typedef __attribute__((ext_vector_type(4))) float f32x4;

static __device__ __forceinline__ unsigned short f2bf(float x) {
    __hip_bfloat16 h = __float2bfloat16(x);   // HW RNE convert
    unsigned short r;
    __builtin_memcpy(&r, &h, sizeof(r));
    return r;
}

// Raw workgroup barrier WITHOUT the vmcnt(0) drain __syncthreads() emits.
#define KBARRIER()                                                \
    do {                                                          \
        asm volatile("s_waitcnt lgkmcnt(0)" ::: "memory");        \
        __builtin_amdgcn_s_barrier();                             \
        asm volatile("" ::: "memory");                            \
    } while (0)

// ---------------------------------------------------------------------------
// Kernel 0: pack W1 (fp32 [768][384]) into MFMA B-fragment layout, bf16 (hi
// only — the filter GEMM is 1-term; exactness is restored by the rescore).
// Fragment element j of lane: B[k = chunk*32 + (lane>>4)*8 + j][n = ntile*16 + (lane&15)]
// packed[( (ntile*KCH + chunk)*64 + lane )*8 + j]  (coalesced: lane stride 16B)
// ---------------------------------------------------------------------------
__global__ __launch_bounds__(64) void pack_w1(const float* __restrict__ W1,
                                              unsigned short* __restrict__ bh)
{
    const int nt   = blockIdx.x;        // 0..23
    const int ch   = blockIdx.y;        // 0..23
    const int lane = threadIdx.x;
    const int n    = nt * 16 + (lane & 15);
    const int k0   = ch * 32 + (lane >> 4) * 8;

    unsigned short h8[8];
#pragma unroll
    for (int j = 0; j < 8; ++j)
        h8[j] = f2bf(W1[(size_t)(k0 + j) * H_ + n]);
    const size_t base = ((size_t)(nt * KCH + ch) * 64 + lane) * 8;
#pragma unroll
    for (int j = 0; j < 8; ++j) bh[base + j] = h8[j];
}

// ---------------------------------------------------------------------------
// Kernel 1: APPROXIMATE fused scores (filter). v6 structure with the bf16
// hi/lo split removed: 1-term plain-bf16 GEMM (12 MFMA/chunk/wave, 6 B
// loads, half the convert VALU). Score error ~0.003 sigma; only the top-128
// ranking per batch is consumed downstream (margin to true top-40 ~100x).
// Block = 32 tokens x 384 cols (grid 2048), 4 waves; wave w owns n-tiles
// w*6..w*6+5 and 2 m-subtiles. launch_bounds(256,5): smaller live set ->
// 5 blocks/CU for more TLP.
// ---------------------------------------------------------------------------
__global__ __launch_bounds__(256, 5) void score_kernel(
    const float* __restrict__ features,
    const unsigned short* __restrict__ bh_g,
    const float* __restrict__ b1,
    const float* __restrict__ gamma,
    const float* __restrict__ beta,
    const float* __restrict__ W2,
    const float* __restrict__ b2,
    float* __restrict__ scores)
{
    __shared__ unsigned short Ah[32][40];   // pad 32->40 (16B-aligned rows)
    __shared__ float red[4][32];
    __shared__ float mu_s[32];
    __shared__ float rs_s[32];

    const int tid  = threadIdx.x;
    const int lane = tid & 63;
    const int w    = tid >> 6;
    const int base = blockIdx.x * 32;
    const int cl   = lane & 15;
    const int p    = lane >> 4;

    f32x4 acc[2][6];
#pragma unroll
    for (int m = 0; m < 2; ++m)
#pragma unroll
        for (int t = 0; t < 6; ++t) acc[m][t] = (f32x4){0.f, 0.f, 0.f, 0.f};

    // staging map: thread covers one float4: row = tid>>3 (0..31), col4 = (tid&7)*4
    const int r0 = tid >> 3, c0 = (tid & 7) * 4;
    const float* arow = features + (size_t)(base + r0) * D_ + c0;

    float4 p0 = *(const float4*)(arow);     // A chunk 0

    for (int c = 0; c < KCH; ++c) {
        if (c) KBARRIER();                  // X: prev readers done
        Ah[r0][c0]   = f2bf(p0.x);
        Ah[r0][c0+1] = f2bf(p0.y);
        Ah[r0][c0+2] = f2bf(p0.z);
        Ah[r0][c0+3] = f2bf(p0.w);
        KBARRIER();                         // Y: LDS chunk c ready

        // prefetch next chunk's A; stays in flight across barriers
        if (c + 1 < KCH) p0 = *(const float4*)(arow + (c + 1) * 32);

        bf16x8 ahf[2];
#pragma unroll
        for (int m = 0; m < 2; ++m)
            ahf[m] = *(const bf16x8*)&Ah[m * 16 + cl][p * 8];
#pragma unroll
        for (int t = 0; t < 6; ++t) {
            const size_t bb = ((size_t)((w * 6 + t) * KCH + c) * 64 + lane) * 8;
            const bf16x8 bhf = *(const bf16x8*)(bh_g + bb);
#pragma unroll
            for (int m = 0; m < 2; ++m)
                acc[m][t] = __builtin_amdgcn_mfma_f32_16x16x32_bf16(ahf[m], bhf, acc[m][t], 0, 0, 0);
        }
    }

    // ---- epilogue: per-column constants ----
    float b1v[6], gv[6], bev[6], w2v[6];
#pragma unroll
    for (int t = 0; t < 6; ++t) {
        const int n = (w * 6 + t) * 16 + cl;
        b1v[t] = b1[n]; gv[t] = gamma[n]; bev[t] = beta[n]; w2v[t] = W2[n];
    }
#pragma unroll
    for (int m = 0; m < 2; ++m)
#pragma unroll
        for (int t = 0; t < 6; ++t)
#pragma unroll
            for (int r = 0; r < 4; ++r) acc[m][t][r] += b1v[t];

    // pass 1: mean
#pragma unroll
    for (int m = 0; m < 2; ++m) {
        float sm[4] = {0.f, 0.f, 0.f, 0.f};
#pragma unroll
        for (int t = 0; t < 6; ++t)
#pragma unroll
            for (int r = 0; r < 4; ++r) sm[r] += acc[m][t][r];
#pragma unroll
        for (int r = 0; r < 4; ++r) {
#pragma unroll
            for (int off = 1; off <= 8; off <<= 1) sm[r] += __shfl_xor(sm[r], off, 64);
        }
        if (cl == 0) {
#pragma unroll
            for (int r = 0; r < 4; ++r) red[w][m * 16 + p * 4 + r] = sm[r];
        }
    }
    __syncthreads();
    if (tid < 32) mu_s[tid] = (red[0][tid] + red[1][tid] + red[2][tid] + red[3][tid]) * (1.0f / H_);
    __syncthreads();

    // pass 2: variance
#pragma unroll
    for (int m = 0; m < 2; ++m) {
        float mur[4];
#pragma unroll
        for (int r = 0; r < 4; ++r) mur[r] = mu_s[m * 16 + p * 4 + r];
        float sm[4] = {0.f, 0.f, 0.f, 0.f};
#pragma unroll
        for (int t = 0; t < 6; ++t)
#pragma unroll
            for (int r = 0; r < 4; ++r) { const float d = acc[m][t][r] - mur[r]; sm[r] += d * d; }
#pragma unroll
        for (int r = 0; r < 4; ++r) {
#pragma unroll
            for (int off = 1; off <= 8; off <<= 1) sm[r] += __shfl_xor(sm[r], off, 64);
        }
        if (cl == 0) {
#pragma unroll
            for (int r = 0; r < 4; ++r) red[w][m * 16 + p * 4 + r] = sm[r];
        }
    }
    __syncthreads();
    if (tid < 32) rs_s[tid] = rsqrtf((red[0][tid] + red[1][tid] + red[2][tid] + red[3][tid]) * (1.0f / H_) + 1e-5f);
    __syncthreads();

    // pass 3: LN + gelu + W2
#pragma unroll
    for (int m = 0; m < 2; ++m) {
        float mur[4], rsr[4];
#pragma unroll
        for (int r = 0; r < 4; ++r) { mur[r] = mu_s[m * 16 + p * 4 + r]; rsr[r] = rs_s[m * 16 + p * 4 + r]; }
        float sm[4] = {0.f, 0.f, 0.f, 0.f};
#pragma unroll
        for (int t = 0; t < 6; ++t)
#pragma unroll
            for (int r = 0; r < 4; ++r) {
                const float y  = (acc[m][t][r] - mur[r]) * rsr[r] * gv[t] + bev[t];
                const float ge = 0.5f * y * (1.0f + erff(y * 0.70710678118654752f));
                sm[r] = fmaf(ge, w2v[t], sm[r]);
            }
#pragma unroll
        for (int r = 0; r < 4; ++r) {
#pragma unroll
            for (int off = 1; off <= 8; off <<= 1) sm[r] += __shfl_xor(sm[r], off, 64);
        }
        if (cl == 0) {
#pragma unroll
            for (int r = 0; r < 4; ++r) red[w][m * 16 + p * 4 + r] = sm[r];
        }
    }
    __syncthreads();
    if (tid < 32) {
        const float s = red[0][tid] + red[1][tid] + red[2][tid] + red[3][tid] + b2[0];
        scores[base + tid] = 1.0f / (1.0f + expf(-s));
    }
}

// ---------------------------------------------------------------------------
// Kernel 2: per-batch top-NCAND(128) candidates via byte-wise radix select on
// approx score bits (scores > 0 so uint order == float order). Ties -> lower
// index. Output order = approx rank (irrelevant: final kernel re-sorts).
// ---------------------------------------------------------------------------
__global__ __launch_bounds__(256) void cand_kernel(const float* __restrict__ scores,
                                                   int* __restrict__ cand)
{
    __shared__ unsigned int bits_s[S_];     // 16 KB
    __shared__ unsigned int hist[256];
    __shared__ unsigned int suf[256];
    __shared__ unsigned int wtot[4];
    __shared__ int s_byte, s_rem;
    __shared__ unsigned int s_ngt, s_neq;
    __shared__ unsigned int candV[NCAND];
    __shared__ int candI[NCAND];
    __shared__ int eqI[256];

    const int b    = blockIdx.x;
    const int tid  = threadIdx.x;
    const int lane = tid & 63;
    const int w4   = tid >> 6;

    for (int i = tid; i < S_; i += 256)
        bits_s[i] = __float_as_uint(scores[b * S_ + i]);
    if (tid == 0) { s_rem = NCAND; s_ngt = 0u; s_neq = 0u; }

    unsigned int prefix = 0u, mask = 0u;
    for (int pb = 3; pb >= 0; --pb) {
        hist[tid] = 0u;
        __syncthreads();
        for (int i = tid; i < S_; i += 256) {
            const unsigned int u = bits_s[i];
            if ((u & mask) == prefix) atomicAdd(&hist[(u >> (8 * pb)) & 255u], 1u);
        }
        __syncthreads();
        {
            unsigned int v = hist[tid];
#pragma unroll
            for (int off = 1; off < 64; off <<= 1) {
                const unsigned int y = __shfl_down(v, off, 64);
                if (lane + off < 64) v += y;
            }
            if (lane == 0) wtot[w4] = v;
            __syncthreads();
            unsigned int add = 0u;
#pragma unroll
            for (int j = 0; j < 4; ++j) if (j > w4) add += wtot[j];
            v += add;
            suf[tid] = v;
            __syncthreads();
            const int rem = s_rem;
            const unsigned int nxt = (tid < 255) ? suf[tid + 1] : 0u;
            if (suf[tid] >= (unsigned)rem && (tid == 255 || nxt < (unsigned)rem)) {
                s_byte = tid;
                s_rem  = rem - (int)nxt;
            }
        }
        __syncthreads();
        prefix |= ((unsigned int)s_byte) << (8 * pb);
        mask   |= 0xFFu << (8 * pb);
        __syncthreads();
    }
    const unsigned int T = prefix;
    const int need = s_rem;                 // 1..: #ties at T to keep

    for (int i = tid; i < S_; i += 256) {
        const unsigned int u = bits_s[i];
        if (u > T) {
            const unsigned int pos = atomicAdd(&s_ngt, 1u);
            candV[pos] = u; candI[pos] = i;          // n_gt <= NCAND-1 guaranteed
        } else if (u == T) {
            const unsigned int pos = atomicAdd(&s_neq, 1u);
            if (pos < 256u) eqI[pos] = i;
        }
    }
    __syncthreads();
    const int ngt = (int)s_ngt;
    const int neq = (int)(s_neq < 256u ? s_neq : 256u);
    for (int j = tid; j < neq; j += 256) {
        int rank = 0;
        for (int l = 0; l < neq; ++l) rank += (eqI[l] < eqI[j]) ? 1 : 0;
        if (rank < need) { candV[ngt + rank] = T; candI[ngt + rank] = eqI[j]; }
    }
    __syncthreads();
    if (tid < NCAND) cand[b * NCAND + tid] = candI[tid];
}

// ---------------------------------------------------------------------------
// Kernel 3: EXACT fp32 rescore of candidates. Grid (16 groups, 16 batches);
// block = 256 threads handles 8 candidates (32 threads each, 12 cols/thread).
// Full pipeline in fp32 VALU: h = x.W1 + b1, LN, exact GELU, dot W2, sigmoid.
// Error ~1e-6 relative — 10x tighter than the 3-term bf16 split that
// repeatedly produced absmax=0 on this data.
// ---------------------------------------------------------------------------
__global__ __launch_bounds__(256) void rescore_kernel(
    const float* __restrict__ features,
    const float* __restrict__ W1,
    const float* __restrict__ b1,
    const float* __restrict__ gamma,
    const float* __restrict__ beta,
    const float* __restrict__ W2,
    const float* __restrict__ b2,
    const int* __restrict__ cand,
    float* __restrict__ escore)
{
    __shared__ float xs[8][D_];             // 24 KB
    __shared__ int cidx[8];

    const int g   = blockIdx.x;             // candidate group 0..15
    const int b   = blockIdx.y;             // batch 0..15
    const int tid = threadIdx.x;

    if (tid < 8) cidx[tid] = cand[b * NCAND + g * 8 + tid];
    __syncthreads();

    // stage the 8 candidate rows (float4-coalesced)
    for (int i = tid; i < 8 * (D_ / 4); i += 256) {
        const int r = i / (D_ / 4);
        const int c = i % (D_ / 4);
        *(float4*)&xs[r][c * 4] =
            *(const float4*)(features + ((size_t)b * S_ + cidx[r]) * D_ + c * 4);
    }
    __syncthreads();

    const int r  = tid >> 5;                // candidate 0..7
    const int ln = tid & 31;                // lane-in-group
    const int n0 = ln * 12;                 // 12 columns per thread

    float h[12];
#pragma unroll
    for (int j = 0; j < 12; ++j) h[j] = b1[n0 + j];

    for (int d = 0; d < D_; ++d) {
        const float xv = xs[r][d];
        const float4 w0 = *(const float4*)(W1 + (size_t)d * H_ + n0);
        const float4 w1 = *(const float4*)(W1 + (size_t)d * H_ + n0 + 4);
        const float4 w2 = *(const float4*)(W1 + (size_t)d * H_ + n0 + 8);
        h[0] = fmaf(xv, w0.x, h[0]);  h[1] = fmaf(xv, w0.y, h[1]);
        h[2] = fmaf(xv, w0.z, h[2]);  h[3] = fmaf(xv, w0.w, h[3]);
        h[4] = fmaf(xv, w1.x, h[4]);  h[5] = fmaf(xv, w1.y, h[5]);
        h[6] = fmaf(xv, w1.z, h[6]);  h[7] = fmaf(xv, w1.w, h[7]);
        h[8] = fmaf(xv, w2.x, h[8]);  h[9] = fmaf(xv, w2.y, h[9]);
        h[10] = fmaf(xv, w2.z, h[10]); h[11] = fmaf(xv, w2.w, h[11]);
    }

    // mean over the 32-lane group
    float sm = 0.f;
#pragma unroll
    for (int j = 0; j < 12; ++j) sm += h[j];
#pragma unroll
    for (int off = 1; off < 32; off <<= 1) sm += __shfl_xor(sm, off, 32);
    const float mu = sm * (1.0f / H_);

    float sv = 0.f;
#pragma unroll
    for (int j = 0; j < 12; ++j) { const float d = h[j] - mu; sv += d * d; }
#pragma unroll
    for (int off = 1; off < 32; off <<= 1) sv += __shfl_xor(sv, off, 32);
    const float rsig = rsqrtf(sv * (1.0f / H_) + 1e-5f);

    float ss = 0.f;
#pragma unroll
    for (int j = 0; j < 12; ++j) {
        const int n = n0 + j;
        const float y  = (h[j] - mu) * rsig * gamma[n] + beta[n];
        const float ge = 0.5f * y * (1.0f + erff(y * 0.70710678118654752f));
        ss = fmaf(ge, W2[n], ss);
    }
#pragma unroll
    for (int off = 1; off < 32; off <<= 1) ss += __shfl_xor(ss, off, 32);

    if (ln == 0) {
        const float s = ss + b2[0];
        escore[b * NCAND + g * 8 + r] = 1.0f / (1.0f + expf(-s));
    }
}

// ---------------------------------------------------------------------------
// Kernel 4: final exact top-40 among the 128 rescored candidates per batch.
// Rank by (score desc, index asc) — matches jax top_k tie semantics.
// ---------------------------------------------------------------------------
__global__ __launch_bounds__(NCAND) void final_kernel(const float* __restrict__ escore,
                                                      const int* __restrict__ cand,
                                                      int* __restrict__ sel)
{
    __shared__ float s_s[NCAND];
    __shared__ int   s_i[NCAND];
    const int b   = blockIdx.x;
    const int tid = threadIdx.x;

    s_s[tid] = escore[b * NCAND + tid];
    s_i[tid] = cand[b * NCAND + tid];
    __syncthreads();

    const float s = s_s[tid];
    const int   idx = s_i[tid];
    int rank = 0;
    for (int l = 0; l < NCAND; ++l)
        rank += (s_s[l] > s || (s_s[l] == s && s_i[l] < idx)) ? 1 : 0;
    if (rank < KTOP) sel[b * KTOP + rank] = idx;
}

// ---------------------------------------------------------------------------
// Kernel 5: gather selected rows + write indices (as float). Grid (40,16).
// ---------------------------------------------------------------------------
__global__ __launch_bounds__(192) void gather_kernel(const float* __restrict__ features,
                                                     const int* __restrict__ sel,
                                                     float* __restrict__ out_tok,
                                                     float* __restrict__ out_idx)
{
    const int i = blockIdx.x;   // 0..39
    const int b = blockIdx.y;   // 0..15
    const int idx = sel[b * KTOP + i];
    const float4* src = (const float4*)(features + ((size_t)b * S_ + idx) * D_);
    float4* dst = (float4*)(out_tok + ((size_t)b * KTOP + i) * D_);
    dst[threadIdx.x] = src[threadIdx.x];
    if (threadIdx.x == 0) out_idx[b * KTOP + i] = (float)idx;
}

// ---------------------------------------------------------------------------
extern "C" void kernel_launch(void* const* d_in, const int* in_sizes, int n_in,
                              void* d_out, int out_size, void* d_ws, size_t ws_size,
                              hipStream_t stream)
{
    const float* features = (const float*)d_in[0];
    const float* W1       = (const float*)d_in[1];
    const float* b1       = (const float*)d_in[2];
    const float* gamma    = (const float*)d_in[3];
    const float* beta     = (const float*)d_in[4];
    const float* W2       = (const float*)d_in[5];
    const float* b2       = (const float*)d_in[6];

    // ws layout
    unsigned short* bh = (unsigned short*)d_ws;              // 294912 shorts (576 KB)
    float* scores      = (float*)(bh + (size_t)D_ * H_);     // 256 KB
    int*   cand        = (int*)(scores + NTOK);              // 8 KB
    float* escore      = (float*)(cand + B_ * NCAND);        // 8 KB
    int*   sel         = (int*)(escore + B_ * NCAND);        // 2.5 KB

    float* out        = (float*)d_out;
    float* out_tokens = out;                                 // [16,40,768]
    float* out_idx    = out + (size_t)B_ * KTOP * D_;        // [16,40]

    pack_w1<<<dim3(NTILES, KCH), 64, 0, stream>>>(W1, bh);
    score_kernel<<<NTOK / 32, 256, 0, stream>>>(features, bh, b1, gamma, beta, W2, b2, scores);
    cand_kernel<<<B_, 256, 0, stream>>>(scores, cand);
    rescore_kernel<<<dim3(B_ * NCAND / (8 * 16), B_), 256, 0, stream>>>(
        features, W1, b1, gamma, beta, W2, b2, cand, escore);
    final_kernel<<<B_, NCAND, 0, stream>>>(escore, cand, sel);
    gather_kernel<<<dim3(KTOP, B_), 192, 0, stream>>>(features, sel, out_tokens, out_idx);
}